// Round 8
// baseline (326.477 us; speedup 1.0000x reference)
//
#include <hip/hip_runtime.h>
#include <stdint.h>

// NCA step v8 = v7 (wave-autonomous 8x8 tiles, zero barriers) with register
// demand cut below the 102-reg / 5-waves-per-SIMD threshold:
//   - __launch_bounds__(256, 5)  (v7's (256,4) let AGPR+VGPR total ~124 ->
//     4 waves/SIMD cap; that residency, not barriers, was the invariant)
//   - no biasv preload (b1[j] reloaded per nt, L1-resident)
//   - no persistent id capture: center tap re-read from halo LDS at pack time
// B=8, C=20, H=W=256, HID=128, K_in=60 (pad 64), steps=4.

#define Bsz 8
#define Cn  20
#define Hn  256
#define Wn  256
#define HW  (Hn*Wn)

typedef float  f32x4  __attribute__((ext_vector_type(4)));
typedef __bf16 bf16x8 __attribute__((ext_vector_type(8)));
typedef __bf16 bf16x4 __attribute__((ext_vector_type(4)));
typedef short  s16x8  __attribute__((ext_vector_type(8)));

// Threefry-2x32, 20 rounds (verified r1: matches jax threefry_partitionable).
__device__ __host__ __forceinline__ void tf2x32(uint32_t k0, uint32_t k1,
                                                uint32_t x0, uint32_t x1,
                                                uint32_t& o0, uint32_t& o1) {
  uint32_t ks2 = k0 ^ k1 ^ 0x1BD11BDAu;
  x0 += k0; x1 += k1;
#define TFR(r) { x0 += x1; x1 = (x1 << (r)) | (x1 >> (32 - (r))); x1 ^= x0; }
  TFR(13) TFR(15) TFR(26) TFR(6)
  x0 += k1;  x1 += ks2 + 1u;
  TFR(17) TFR(29) TFR(16) TFR(24)
  x0 += ks2; x1 += k0 + 2u;
  TFR(13) TFR(15) TFR(26) TFR(6)
  x0 += k0;  x1 += k1 + 3u;
  TFR(17) TFR(29) TFR(16) TFR(24)
  x0 += k1;  x1 += ks2 + 4u;
  TFR(13) TFR(15) TFR(26) TFR(6)
  x0 += ks2; x1 += k0 + 5u;
#undef TFR
  o0 = x0; o1 = x1;
}

__device__ __forceinline__ f32x4 mfma16(bf16x8 a, bf16x8 b, f32x4 c) {
  return __builtin_amdgcn_mfma_f32_16x16x32_bf16(
      __builtin_bit_cast(s16x8, a), __builtin_bit_cast(s16x8, b), c, 0, 0, 0);
}

// W1p: GEMM1 B-fragments. i = (((ch*2+nt)*2+kb)*64 + l)*8 + e:
//   j = ch*32+nt*16+(l&15), k = kb*32+(l>>4)*8+e  -> W1[j][k] (k<60 else 0)
// W2p: GEMM2 A-fragments (A = W2, m = channel). i = ((mt*4+kb)*64+l)*8+e:
//   ch = mt*16+(l&15), j = kb*32+(l>>4)*8+e -> W2[ch][j] for 3<=ch<20 else 0
__global__ void pack_weights(const float* __restrict__ W1, const float* __restrict__ W2,
                             __bf16* __restrict__ W1p, __bf16* __restrict__ W2p) {
  int t = blockIdx.x * 256 + threadIdx.x;
  for (int i = t; i < 128 * 64; i += gridDim.x * 256) {
    int e = i & 7, l = (i >> 3) & 63, kb = (i >> 9) & 1, nt = (i >> 10) & 1, ch = i >> 11;
    int j = ch * 32 + nt * 16 + (l & 15);
    int k = kb * 32 + (l >> 4) * 8 + e;
    W1p[i] = (k < 60) ? (__bf16)W1[j * 60 + k] : (__bf16)0.f;
  }
  for (int i = t; i < 2 * 4 * 64 * 8; i += gridDim.x * 256) {
    int e = i & 7, l = (i >> 3) & 63, kb = (i >> 9) & 3, mt = (i >> 11) & 1;
    int ch = mt * 16 + (l & 15);
    int j  = kb * 32 + (l >> 4) * 8 + e;
    W2p[i] = (ch >= 3 && ch < Cn) ? (__bf16)W2[ch * 128 + j] : (__bf16)0.f;
  }
}

template <bool PRE>
__global__ __launch_bounds__(256, 5) void nca_step(
    const float* __restrict__ xin, float* __restrict__ xout,
    const float* __restrict__ wf1, const float* __restrict__ wf2,
    const float* __restrict__ W1, const float* __restrict__ b1,
    const float* __restrict__ W2,
    const __bf16* __restrict__ W1b, const __bf16* __restrict__ W2b,
    uint32_t ka, uint32_t kb_key) {

  // 4 waves x 2560 bf16 (5120 B) wave-PRIVATE slices, time-overlaid:
  //   early: halo tile [100 px][24 ch] bf16 (4800 B)
  //   late : r1 [64 rows][40 cols] bf16 -- perc chunks / H chunks
  // No cross-wave sharing -> no __syncthreads anywhere.
  __shared__ __align__(16) __bf16 smem[4 * 2560];

  const int tid = threadIdx.x;
  const int w = tid >> 6, l = tid & 63;
  __bf16* lds = smem + w * 2560;

  // XCD swizzle: round-robin dispatch -> XCD k handles batch image k.
  const int lin = (blockIdx.z * 16 + blockIdx.y) * 16 + blockIdx.x;
  const int swzb = (lin & 7) * 256 + (lin >> 3);
  const int b  = swzb >> 8;
  const int by = ((swzb >> 4) & 15) * 16;
  const int bx = (swzb & 15) * 16;
  // wave quadrant of the block's 16x16 region -> 8x8 tile origin
  const int by0 = by + (w >> 1) * 8;
  const int bx0 = bx + (w & 1) * 8;

  const float* __restrict__ xb = xin + (size_t)b * Cn * HW;

  // ---- Stage 10x10 halo (reflect) as bf16, channel-interleaved, wave-local ----
#pragma unroll
  for (int s = 0; s < 2; ++s) {
    int h = l + s * 64;
    if (h < 100) {
      int hy = h / 10, hx = h - hy * 10;
      int gy = by0 - 1 + hy; gy = (gy < 0) ? -gy : ((gy >= Hn) ? 2 * Hn - 2 - gy : gy);
      int gx = bx0 - 1 + hx; gx = (gx < 0) ? -gx : ((gx >= Wn) ? 2 * Wn - 2 - gx : gx);
      const float* sp = xb + (size_t)gy * Wn + gx;
      bf16x8 q0, q1; bf16x4 q2;
#pragma unroll
      for (int c = 0; c < 8; ++c)  q0[c] = (__bf16)sp[(size_t)c * HW];
#pragma unroll
      for (int c = 0; c < 8; ++c)  q1[c] = (__bf16)sp[(size_t)(c + 8) * HW];
#pragma unroll
      for (int c = 0; c < 4; ++c)  q2[c] = (__bf16)sp[(size_t)(c + 16) * HW];
      __bf16* wp = lds + h * 24;
      *(bf16x8*)(wp)      = q0;
      *(bf16x8*)(wp + 8)  = q1;
      *(bf16x4*)(wp + 16) = q2;
    }
  }

  // Fire mask in the load shadow: lane l owns pixel px=l (y=l>>3, x=l&7).
  const int py = l >> 3, px_ = l & 7;
  uint32_t y0, y1;
  tf2x32(ka, kb_key, 0u, (uint32_t)((b * Hn + by0 + py) * Wn + bx0 + px_), y0, y1);
  const unsigned long long fmask = __ballot(((y0 ^ y1) & 0x80000000u) == 0u);

  // ---- Depthwise conv (fp32 math, bf16 taps); own pixel only ----
  float a1[Cn], a2[Cn];
#pragma unroll
  for (int c = 0; c < Cn; ++c) { a1[c] = 0.f; a2[c] = 0.f; }

#pragma unroll
  for (int ky = 0; ky < 3; ++ky)
#pragma unroll
    for (int kx = 0; kx < 3; ++kx) {
      const __bf16* tp = lds + ((py + ky) * 10 + px_ + kx) * 24;
      bf16x8 t0 = *(const bf16x8*)(tp);
      bf16x8 t1 = *(const bf16x8*)(tp + 8);
      bf16x4 t2 = *(const bf16x4*)(tp + 16);
      const int tap = ky * 3 + kx;
#pragma unroll
      for (int c = 0; c < 8; ++c) {
        float v = (float)t0[c];
        a1[c] = fmaf(wf1[c * 9 + tap], v, a1[c]);
        a2[c] = fmaf(wf2[c * 9 + tap], v, a2[c]);
      }
#pragma unroll
      for (int c = 0; c < 8; ++c) {
        float v = (float)t1[c];
        a1[c + 8] = fmaf(wf1[(c + 8) * 9 + tap], v, a1[c + 8]);
        a2[c + 8] = fmaf(wf2[(c + 8) * 9 + tap], v, a2[c + 8]);
      }
#pragma unroll
      for (int c = 0; c < 4; ++c) {
        float v = (float)t2[c];
        a1[c + 16] = fmaf(wf1[(c + 16) * 9 + tap], v, a1[c + 16]);
        a2[c + 16] = fmaf(wf2[(c + 16) * 9 + tap], v, a2[c + 16]);
      }
    }

  // ---- Pack perc -> r1 (time-shared 32-k chunks), load A-fragments (M=64) ----
  // Identity slots (k<20) are RE-READ from the halo (still intact: pack reads
  // precede pack writes in program order) instead of held in regs since conv.
  const int g4 = l >> 4, c16 = l & 15;

  bf16x8 af[4][2];
#pragma unroll
  for (int kb = 0; kb < 2; ++kb) {
    bf16x8 id0; bf16x8 id1; bf16x4 id2;
    if (kb == 0) {
      const __bf16* ctr = lds + ((py + 1) * 10 + px_ + 1) * 24;
      id0 = *(const bf16x8*)(ctr);
      id1 = *(const bf16x8*)(ctr + 8);
      id2 = *(const bf16x4*)(ctr + 16);
    }
#pragma unroll
    for (int g2 = 0; g2 < 4; ++g2) {
      bf16x8 pk;
#pragma unroll
      for (int e = 0; e < 8; ++e) {
        const int k = kb * 32 + g2 * 8 + e;
        __bf16 v;
        if      (k < 8)  v = id0[k];
        else if (k < 16) v = id1[k - 8];
        else if (k < 20) v = id2[k - 16];
        else if (k < 40) v = (__bf16)a1[k - 20];
        else if (k < 60) v = (__bf16)a2[k - 40];
        else             v = (__bf16)0.f;
        pk[e] = v;
      }
      *(bf16x8*)(lds + l * 40 + g2 * 8) = pk;   // own row l (overlays halo)
    }
    // same-wave LDS ordering: all lanes' writes precede these reads
#pragma unroll
    for (int mt = 0; mt < 4; ++mt)
      af[mt][kb] = *(const bf16x8*)(lds + (mt * 16 + c16) * 40 + g4 * 8);
  }

  // ---- GEMM chunks: per 32 j's: GEMM1 -> H chunk (LDS) -> GEMM2 (swapped) ----
  const f32x4 zero4 = {0.f, 0.f, 0.f, 0.f};
  f32x4 acc2[2][4];   // [mt: ch 0..15 / 16..31][nt: 16-px groups of the 64 px]
#pragma unroll
  for (int mt = 0; mt < 2; ++mt)
#pragma unroll
    for (int nt = 0; nt < 4; ++nt) acc2[mt][nt] = zero4;

  const bf16x8* w1v = (const bf16x8*)W1b;
  const bf16x8* w2v = (const bf16x8*)W2b;

  for (int ch4 = 0; ch4 < 4; ++ch4) {
    // GEMM1 chunk: H[64 x 32j] = perc @ W1_chunk^T
#pragma unroll
    for (int nt = 0; nt < 2; ++nt) {
      bf16x8 bw0, bw1;
      if constexpr (PRE) {
        bw0 = w1v[((ch4 * 2 + nt) * 2 + 0) * 64 + l];
        bw1 = w1v[((ch4 * 2 + nt) * 2 + 1) * 64 + l];
      } else {
        const int j = ch4 * 32 + nt * 16 + c16;
        const float* rp = W1 + j * 60;
#pragma unroll
        for (int kb = 0; kb < 2; ++kb) {
          int ks = kb * 32 + g4 * 8;
          f32x4 lo = *(const f32x4*)(rp + ks);
          int ks2 = (ks == 56) ? 52 : ks + 4;
          f32x4 hi = *(const f32x4*)(rp + ks2);
          hi = (ks == 56) ? zero4 : hi;
          bf16x8 pk;
#pragma unroll
          for (int e = 0; e < 4; ++e) { pk[e] = (__bf16)lo[e]; pk[e + 4] = (__bf16)hi[e]; }
          if (kb == 0) bw0 = pk; else bw1 = pk;
        }
      }
      const float bias = b1[ch4 * 32 + nt * 16 + c16];   // L1-resident reload
#pragma unroll
      for (int mt = 0; mt < 4; ++mt) {
        f32x4 a = mfma16(af[mt][0], bw0, zero4);
        a = mfma16(af[mt][1], bw1, a);
#pragma unroll
        for (int r = 0; r < 4; ++r) {
          float hv = fmaxf(a[r] + bias, 0.f);
          lds[(mt * 16 + g4 * 4 + r) * 40 + nt * 16 + c16] = (__bf16)hv;
        }
      }
    }
    // GEMM2 (swapped): dx[ch][px] += W2_chunk @ H_chunk^T
    bf16x8 wa[2];
#pragma unroll
    for (int mt = 0; mt < 2; ++mt) {
      if constexpr (PRE) {
        wa[mt] = w2v[(mt * 4 + ch4) * 64 + l];
      } else {
        const int chl = mt * 16 + c16;
        bf16x8 pk;
        if (chl >= 3 && chl < Cn) {
          const float* rp2 = W2 + (size_t)chl * 128 + ch4 * 32 + g4 * 8;
          f32x4 lo = *(const f32x4*)(rp2);
          f32x4 hi = *(const f32x4*)(rp2 + 4);
#pragma unroll
          for (int e = 0; e < 4; ++e) { pk[e] = (__bf16)lo[e]; pk[e + 4] = (__bf16)hi[e]; }
        } else {
#pragma unroll
          for (int e = 0; e < 8; ++e) pk[e] = (__bf16)0.f;
        }
        wa[mt] = pk;
      }
    }
#pragma unroll
    for (int nt = 0; nt < 4; ++nt) {
      // B-fragment: lane holds H[px = nt*16+(l&15)][j-octet (l>>4)*8]
      bf16x8 hb = *(const bf16x8*)(lds + (nt * 16 + c16) * 40 + g4 * 8);
#pragma unroll
      for (int mt = 0; mt < 2; ++mt)
        acc2[mt][nt] = mfma16(wa[mt], hb, acc2[mt][nt]);
    }
  }

  // ---- Epilogue: D lane layout = (px = nt*16+(l&15), ch = mt*16+g4*4+r).
  // W2 rows <3 / >=20 are zero-padded -> image channels pass through exactly.
  float* __restrict__ ob = xout + (size_t)b * Cn * HW;
#pragma unroll
  for (int nt = 0; nt < 4; ++nt) {
    const int pxl = nt * 16 + c16;                         // pixel 0..63 in tile
    const int gy = by0 + (pxl >> 3), gx = bx0 + (pxl & 7);
    const size_t pix = (size_t)gy * Wn + gx;
    const float fire = ((fmask >> pxl) & 1ull) ? 1.f : 0.f;
#pragma unroll
    for (int mt = 0; mt < 2; ++mt)
#pragma unroll
      for (int r = 0; r < 4; ++r) {
        const int ch = mt * 16 + g4 * 4 + r;
        if (ch < Cn) {
          const size_t off = (size_t)ch * HW + pix;
          ob[off] = xb[off] + acc2[mt][nt][r] * fire;
        }
      }
  }
}

extern "C" void kernel_launch(void* const* d_in, const int* in_sizes, int n_in,
                              void* d_out, int out_size, void* d_ws, size_t ws_size,
                              hipStream_t stream) {
  const float* x   = (const float*)d_in[0];
  const float* wf1 = (const float*)d_in[1];
  const float* wf2 = (const float*)d_in[2];
  const float* W1  = (const float*)d_in[3];
  const float* b1  = (const float*)d_in[4];
  const float* W2  = (const float*)d_in[5];
  const int steps = 4;

  float* out = (float*)d_out;
  float* ws0 = (float*)d_ws;                       // 41,943,040 B ping buffer
  const size_t PING = (size_t)Bsz * Cn * HW * 4;
  const size_t WNEED = PING + (128 * 64 + 2 * 4 * 64 * 8) * sizeof(__bf16);
  const bool pre = (ws_size >= WNEED);
  __bf16* W1p = pre ? (__bf16*)((char*)d_ws + PING) : nullptr;
  __bf16* W2p = pre ? W1p + 128 * 64 : nullptr;

  if (pre) pack_weights<<<8, 256, 0, stream>>>(W1, W2, W1p, W2p);

  dim3 grid(16, 16, Bsz);
  dim3 blk(256);

  const float* src = x;
  for (int s = 0; s < steps; ++s) {
    uint32_t ka, kb;
    tf2x32(0u, 42u, 0u, (uint32_t)s, ka, kb);      // fold_in(key(42), s)
    float* dst = (((steps - s) % 2) == 1) ? out : ws0;
    if (pre) nca_step<true ><<<grid, blk, 0, stream>>>(src, dst, wf1, wf2, W1, b1, W2, W1p, W2p, ka, kb);
    else     nca_step<false><<<grid, blk, 0, stream>>>(src, dst, wf1, wf2, W1, b1, W2, W1p, W2p, ka, kb);
    src = dst;
  }
}

// Round 9
// 237.413 us; speedup vs baseline: 1.3751x; 1.3751x over previous
//
#include <hip/hip_runtime.h>
#include <stdint.h>

// NCA step v9: conv FOLDED INTO GEMM1 (im2col over the LDS halo tile).
// h = relu(Weff @ im2col(x) + b1), Weff[j][tap*24+c] = W1c1*wf1 + W1c2*wf2
// (+ W1x at center tap), prepacked to bf16 fragments in a __device__ global.
// Wave-autonomous 8x8 tiles, zero barriers (v7 scheme). GEMM1 swapped
// (A=Weff, B=halo) so H stores are b64; GEMM2 as v7 (A=W2, B=H).
// B=8, C=20, H=W=256, HID=128, K_eff=216 (pad 224), steps=4.

#define Bsz 8
#define Cn  20
#define Hn  256
#define Wn  256
#define HW  (Hn*Wn)

typedef float  f32x4  __attribute__((ext_vector_type(4)));
typedef __bf16 bf16x8 __attribute__((ext_vector_type(8)));
typedef __bf16 bf16x4 __attribute__((ext_vector_type(4)));
typedef short  s16x8  __attribute__((ext_vector_type(8)));

// Prepacked weights (persist across launches; rewritten deterministically
// by pack_weights at the start of every kernel_launch).
__device__ __bf16 g_W1p[4 * 2 * 7 * 64 * 8];   // 28672: GEMM1 A-fragments (Weff)
__device__ __bf16 g_W2p[2 * 4 * 64 * 8];       //  4096: GEMM2 A-fragments (W2)

// Threefry-2x32, 20 rounds (verified r1: matches jax threefry_partitionable).
__device__ __host__ __forceinline__ void tf2x32(uint32_t k0, uint32_t k1,
                                                uint32_t x0, uint32_t x1,
                                                uint32_t& o0, uint32_t& o1) {
  uint32_t ks2 = k0 ^ k1 ^ 0x1BD11BDAu;
  x0 += k0; x1 += k1;
#define TFR(r) { x0 += x1; x1 = (x1 << (r)) | (x1 >> (32 - (r))); x1 ^= x0; }
  TFR(13) TFR(15) TFR(26) TFR(6)
  x0 += k1;  x1 += ks2 + 1u;
  TFR(17) TFR(29) TFR(16) TFR(24)
  x0 += ks2; x1 += k0 + 2u;
  TFR(13) TFR(15) TFR(26) TFR(6)
  x0 += k0;  x1 += k1 + 3u;
  TFR(17) TFR(29) TFR(16) TFR(24)
  x0 += k1;  x1 += ks2 + 4u;
  TFR(13) TFR(15) TFR(26) TFR(6)
  x0 += ks2; x1 += k0 + 5u;
#undef TFR
  o0 = x0; o1 = x1;
}

__device__ __forceinline__ f32x4 mfma16(bf16x8 a, bf16x8 b, f32x4 c) {
  return __builtin_amdgcn_mfma_f32_16x16x32_bf16(
      __builtin_bit_cast(s16x8, a), __builtin_bit_cast(s16x8, b), c, 0, 0, 0);
}

// Halo-tile byte-element offset for im2col octet o (o = k/8, k = tap*24+c):
// tap = o/3 -> (dy,dx); channel octet = o%3. o==27 is the K-pad (weights are
// zero there) -> safe offset 0.
__host__ __device__ constexpr int toff_o(int o) {
  return (o >= 27) ? 0
         : (((o / 3) / 3) * 10 + ((o / 3) % 3)) * 24 + (o % 3) * 8;
}

// W1p: i = (((q*2+mt)*7+kb)*512 + l*8 + e):
//   j = q*32 + mt*16 + (l&15);  k = kb*32 + (l>>4)*8 + e
//   Weff[j][k]: k=tap*24+c; c<20: W1[j][20+c]*wf1[c*9+tap]
//                                + W1[j][40+c]*wf2[c*9+tap] + (tap==4)*W1[j][c]
// W2p: i = ((mt*4+q)*512 + l*8 + e): ch = mt*16+(l&15), j = q*32+(l>>4)*8+e;
//   = W2[ch][j] for 3<=ch<20 else 0.
__global__ void pack_weights(const float* __restrict__ W1, const float* __restrict__ wf1,
                             const float* __restrict__ wf2, const float* __restrict__ W2) {
  int t = blockIdx.x * 256 + threadIdx.x;
  for (int i = t; i < 4 * 2 * 7 * 512; i += gridDim.x * 256) {
    int e = i & 7, l = (i >> 3) & 63;
    int blk = i >> 9;                  // (q*2+mt)*7 + kb
    int kb = blk % 7, qm = blk / 7;
    int mt = qm & 1, q = qm >> 1;
    int j = q * 32 + mt * 16 + (l & 15);
    int k = kb * 32 + (l >> 4) * 8 + e;
    float v = 0.f;
    if (k < 216) {
      int tap = k / 24, c = k % 24;
      if (c < 20) {
        v = W1[j * 60 + 20 + c] * wf1[c * 9 + tap]
          + W1[j * 60 + 40 + c] * wf2[c * 9 + tap];
        if (tap == 4) v += W1[j * 60 + c];
      }
    }
    g_W1p[i] = (__bf16)v;
  }
  for (int i = t; i < 2 * 4 * 512; i += gridDim.x * 256) {
    int e = i & 7, l = (i >> 3) & 63, q = (i >> 9) & 3, mt = i >> 11;
    int ch = mt * 16 + (l & 15);
    int j  = q * 32 + (l >> 4) * 8 + e;
    g_W2p[i] = (ch >= 3 && ch < Cn) ? (__bf16)W2[ch * 128 + j] : (__bf16)0.f;
  }
}

__global__ __launch_bounds__(256, 4) void nca_step(
    const float* __restrict__ xin, float* __restrict__ xout,
    const float* __restrict__ b1, uint32_t ka, uint32_t kb_key) {

  // 4 waves x 4960 bf16 (9920 B) wave-PRIVATE slices, no barriers:
  //   halo [100 px][24 ch] bf16 (2400 el) -- lives through all of GEMM1
  //   hq   [64 px][40 cols] bf16 (2560 el) -- H quarter, reused 4x
  __shared__ __align__(16) __bf16 smem[4 * 4960];

  const int tid = threadIdx.x;
  const int w = tid >> 6, l = tid & 63;
  __bf16* halo = smem + w * 4960;
  __bf16* hq   = halo + 2400;

  // XCD swizzle: round-robin dispatch -> XCD k handles batch image k.
  const int lin = (blockIdx.z * 16 + blockIdx.y) * 16 + blockIdx.x;
  const int swzb = (lin & 7) * 256 + (lin >> 3);
  const int b  = swzb >> 8;
  const int by = ((swzb >> 4) & 15) * 16;
  const int bx = (swzb & 15) * 16;
  const int by0 = by + (w >> 1) * 8;
  const int bx0 = bx + (w & 1) * 8;

  const float* __restrict__ xb = xin + (size_t)b * Cn * HW;

  // ---- Stage 10x10 halo (reflect) as bf16, channel-interleaved pitch 24.
  // Slots 20..23 MUST be zeroed: stale LDS could be NaN and MFMA computes
  // 0*NaN = NaN even where Weff is zero.
#pragma unroll
  for (int s = 0; s < 2; ++s) {
    int h = l + s * 64;
    if (h < 100) {
      int hy = h / 10, hx = h - hy * 10;
      int gy = by0 - 1 + hy; gy = (gy < 0) ? -gy : ((gy >= Hn) ? 2 * Hn - 2 - gy : gy);
      int gx = bx0 - 1 + hx; gx = (gx < 0) ? -gx : ((gx >= Wn) ? 2 * Wn - 2 - gx : gx);
      const float* sp = xb + (size_t)gy * Wn + gx;
      bf16x8 q0, q1; bf16x4 q2, qz;
#pragma unroll
      for (int c = 0; c < 8; ++c)  q0[c] = (__bf16)sp[(size_t)c * HW];
#pragma unroll
      for (int c = 0; c < 8; ++c)  q1[c] = (__bf16)sp[(size_t)(c + 8) * HW];
#pragma unroll
      for (int c = 0; c < 4; ++c)  q2[c] = (__bf16)sp[(size_t)(c + 16) * HW];
#pragma unroll
      for (int c = 0; c < 4; ++c)  qz[c] = (__bf16)0.f;
      __bf16* wp = halo + h * 24;
      *(bf16x8*)(wp)      = q0;
      *(bf16x8*)(wp + 8)  = q1;
      *(bf16x4*)(wp + 16) = q2;
      *(bf16x4*)(wp + 20) = qz;
    }
  }

  // Fire mask in the load shadow: lane l owns pixel px=l (y=l>>3, x=l&7).
  const int py = l >> 3, px_ = l & 7;
  uint32_t y0, y1;
  tf2x32(ka, kb_key, 0u, (uint32_t)((b * Hn + by0 + py) * Wn + bx0 + px_), y0, y1);
  const unsigned long long fmask = __ballot(((y0 ^ y1) & 0x80000000u) == 0u);

  const int g4 = l >> 4, c16 = l & 15;
  // B-fragment pixel base for n-tile nt: pixel = nt*16 + c16 ->
  // (py = nt*2 + (c16>>3), px = c16&7); base0 covers the c16 part, +480/nt.
  const int base0 = ((c16 >> 3) * 10 + (c16 & 7)) * 24;

  const bf16x8* w1v = (const bf16x8*)g_W1p;
  const bf16x8* w2v = (const bf16x8*)g_W2p;
  const f32x4 zero4 = {0.f, 0.f, 0.f, 0.f};

  f32x4 acc2[2][4];
#pragma unroll
  for (int mt = 0; mt < 2; ++mt)
#pragma unroll
    for (int nt = 0; nt < 4; ++nt) acc2[mt][nt] = zero4;

  for (int q = 0; q < 4; ++q) {
    // ---- GEMM1 quarter (swapped): H^T-ish D = Weff_q[32j] @ im2col[224k x 64px]
    f32x4 acc1[2][4];
#pragma unroll
    for (int mt = 0; mt < 2; ++mt)
#pragma unroll
      for (int nt = 0; nt < 4; ++nt) acc1[mt][nt] = zero4;

#pragma unroll
    for (int kb = 0; kb < 7; ++kb) {
      bf16x8 aw0 = w1v[((q * 2 + 0) * 7 + kb) * 64 + l];
      bf16x8 aw1 = w1v[((q * 2 + 1) * 7 + kb) * 64 + l];
      // per-lane im2col offset: octet o = kb*4 + g4 (compile-time kb,
      // 4-way select on g4 -> folded constants)
      const int T = (g4 == 0) ? toff_o(kb * 4 + 0)
                  : (g4 == 1) ? toff_o(kb * 4 + 1)
                  : (g4 == 2) ? toff_o(kb * 4 + 2)
                              : toff_o(kb * 4 + 3);
#pragma unroll
      for (int nt = 0; nt < 4; ++nt) {
        bf16x8 hb = *(const bf16x8*)(halo + base0 + nt * 480 + T);
        acc1[0][nt] = mfma16(aw0, hb, acc1[0][nt]);
        acc1[1][nt] = mfma16(aw1, hb, acc1[1][nt]);
      }
    }

    // ---- bias + relu + store H quarter (b64: 4 consecutive j per lane) ----
#pragma unroll
    for (int mt = 0; mt < 2; ++mt) {
      const f32x4 bias = *(const f32x4*)(b1 + q * 32 + mt * 16 + g4 * 4);
#pragma unroll
      for (int nt = 0; nt < 4; ++nt) {
        bf16x4 hv;
#pragma unroll
        for (int r = 0; r < 4; ++r)
          hv[r] = (__bf16)fmaxf(acc1[mt][nt][r] + bias[r], 0.f);
        *(bf16x4*)(hq + (nt * 16 + c16) * 40 + mt * 16 + g4 * 4) = hv;
      }
    }

    // ---- GEMM2 partial: dx[32ch x 64px] += W2_q @ H_q (same-wave LDS order) ----
    bf16x8 wa0 = w2v[(0 * 4 + q) * 64 + l];
    bf16x8 wa1 = w2v[(1 * 4 + q) * 64 + l];
#pragma unroll
    for (int nt = 0; nt < 4; ++nt) {
      bf16x8 hb = *(const bf16x8*)(hq + (nt * 16 + c16) * 40 + g4 * 8);
      acc2[0][nt] = mfma16(wa0, hb, acc2[0][nt]);
      acc2[1][nt] = mfma16(wa1, hb, acc2[1][nt]);
    }
  }

  // ---- Epilogue: D lane layout = (px = nt*16+c16, ch = mt*16+g4*4+r).
  // W2 rows <3 / >=20 zero-padded -> image channels pass through exactly.
  float* __restrict__ ob = xout + (size_t)b * Cn * HW;
#pragma unroll
  for (int nt = 0; nt < 4; ++nt) {
    const int pxl = nt * 16 + c16;
    const int gy = by0 + (pxl >> 3), gx = bx0 + (pxl & 7);
    const size_t pix = (size_t)gy * Wn + gx;
    const float fire = ((fmask >> pxl) & 1ull) ? 1.f : 0.f;
#pragma unroll
    for (int mt = 0; mt < 2; ++mt)
#pragma unroll
      for (int r = 0; r < 4; ++r) {
        const int ch = mt * 16 + g4 * 4 + r;
        if (ch < Cn) {
          const size_t off = (size_t)ch * HW + pix;
          ob[off] = xb[off] + acc2[mt][nt][r] * fire;
        }
      }
  }
}

extern "C" void kernel_launch(void* const* d_in, const int* in_sizes, int n_in,
                              void* d_out, int out_size, void* d_ws, size_t ws_size,
                              hipStream_t stream) {
  const float* x   = (const float*)d_in[0];
  const float* wf1 = (const float*)d_in[1];
  const float* wf2 = (const float*)d_in[2];
  const float* W1  = (const float*)d_in[3];
  const float* b1  = (const float*)d_in[4];
  const float* W2  = (const float*)d_in[5];
  const int steps = 4;

  float* out = (float*)d_out;
  float* ws0 = (float*)d_ws;   // 41.94 MB ping buffer (fits: prior rounds ok)

  pack_weights<<<64, 256, 0, stream>>>(W1, wf1, wf2, W2);

  dim3 grid(16, 16, Bsz);
  dim3 blk(256);

  const float* src = x;
  for (int s = 0; s < steps; ++s) {
    uint32_t ka, kb;
    tf2x32(0u, 42u, 0u, (uint32_t)s, ka, kb);   // fold_in(key(42), s)
    float* dst = (((steps - s) % 2) == 1) ? out : ws0;
    nca_step<<<grid, blk, 0, stream>>>(src, dst, b1, ka, kb);
    src = dst;
  }
}

// Round 10
// 151.609 us; speedup vs baseline: 2.1534x; 1.5660x over previous
//
#include <hip/hip_runtime.h>
#include <stdint.h>

// NCA step v10 = v7 compute core (wave-autonomous 8x8 tiles, conv+perc GEMM,
// zero barriers) + PLANE intermediate layout: state between steps stored as
// 5 planes of [b][pixel][4ch] fp32 (coalesced dwordx4 at both ends) instead
// of NCHW (20 strided dwords per pixel). Step 0 reads NCHW x; step 3 writes
// NCHW out. d_ws and d_out ping-pong as plane buffers.
// B=8, C=20, H=W=256, HID=128, K_in=60 (pad 64), steps=4.

#define Bsz 8
#define Cn  20
#define Hn  256
#define Wn  256
#define HW  (Hn*Wn)

typedef float  f32x4  __attribute__((ext_vector_type(4)));
typedef __bf16 bf16x8 __attribute__((ext_vector_type(8)));
typedef __bf16 bf16x4 __attribute__((ext_vector_type(4)));
typedef short  s16x8  __attribute__((ext_vector_type(8)));

// Prepacked MFMA weight fragments + conv filters (rewritten each launch).
__device__ __bf16 g_W1p[128 * 64];        // GEMM1 B-frags (v7 layout)
__device__ __bf16 g_W2p[2 * 4 * 64 * 8];  // GEMM2 A-frags (v7 layout)
__device__ float  g_wf1[Cn * 9];
__device__ float  g_wf2[Cn * 9];

// Threefry-2x32, 20 rounds (verified r1: matches jax threefry_partitionable).
__device__ __host__ __forceinline__ void tf2x32(uint32_t k0, uint32_t k1,
                                                uint32_t x0, uint32_t x1,
                                                uint32_t& o0, uint32_t& o1) {
  uint32_t ks2 = k0 ^ k1 ^ 0x1BD11BDAu;
  x0 += k0; x1 += k1;
#define TFR(r) { x0 += x1; x1 = (x1 << (r)) | (x1 >> (32 - (r))); x1 ^= x0; }
  TFR(13) TFR(15) TFR(26) TFR(6)
  x0 += k1;  x1 += ks2 + 1u;
  TFR(17) TFR(29) TFR(16) TFR(24)
  x0 += ks2; x1 += k0 + 2u;
  TFR(13) TFR(15) TFR(26) TFR(6)
  x0 += k0;  x1 += k1 + 3u;
  TFR(17) TFR(29) TFR(16) TFR(24)
  x0 += k1;  x1 += ks2 + 4u;
  TFR(13) TFR(15) TFR(26) TFR(6)
  x0 += ks2; x1 += k0 + 5u;
#undef TFR
  o0 = x0; o1 = x1;
}

__device__ __forceinline__ f32x4 mfma16(bf16x8 a, bf16x8 b, f32x4 c) {
  return __builtin_amdgcn_mfma_f32_16x16x32_bf16(
      __builtin_bit_cast(s16x8, a), __builtin_bit_cast(s16x8, b), c, 0, 0, 0);
}

// W1p: GEMM1 B-fragments. i = (((ch*2+nt)*2+kb)*64 + l)*8 + e:
//   j = ch*32+nt*16+(l&15), k = kb*32+(l>>4)*8+e  -> W1[j][k] (k<60 else 0)
// W2p: GEMM2 A-fragments (A = W2, m = channel). i = ((mt*4+kb)*64+l)*8+e:
//   ch = mt*16+(l&15), j = kb*32+(l>>4)*8+e -> W2[ch][j] for 3<=ch<20 else 0
__global__ void pack_weights(const float* __restrict__ W1, const float* __restrict__ W2,
                             const float* __restrict__ wf1, const float* __restrict__ wf2) {
  int t = blockIdx.x * 256 + threadIdx.x;
  for (int i = t; i < 128 * 64; i += gridDim.x * 256) {
    int e = i & 7, l = (i >> 3) & 63, kb = (i >> 9) & 1, nt = (i >> 10) & 1, ch = i >> 11;
    int j = ch * 32 + nt * 16 + (l & 15);
    int k = kb * 32 + (l >> 4) * 8 + e;
    g_W1p[i] = (k < 60) ? (__bf16)W1[j * 60 + k] : (__bf16)0.f;
  }
  for (int i = t; i < 2 * 4 * 64 * 8; i += gridDim.x * 256) {
    int e = i & 7, l = (i >> 3) & 63, kb = (i >> 9) & 3, mt = (i >> 11) & 1;
    int ch = mt * 16 + (l & 15);
    int j  = kb * 32 + (l >> 4) * 8 + e;
    g_W2p[i] = (ch >= 3 && ch < Cn) ? (__bf16)W2[ch * 128 + j] : (__bf16)0.f;
  }
  for (int i = t; i < Cn * 9; i += gridDim.x * 256) {
    g_wf1[i] = wf1[i];
    g_wf2[i] = wf2[i];
  }
}

// SIN/SOUT: 0 = NCHW fp32 (harness x / final out), 1 = PLANE fp32
// (5 planes of [b][pixel][4ch], our intermediate layout).
template <int SIN, int SOUT>
__global__ __launch_bounds__(256, 4) void nca_step(
    const float* __restrict__ src, float* __restrict__ dst,
    const float* __restrict__ b1, uint32_t ka, uint32_t kb_key) {

  // 4 waves x 2560 bf16 (5120 B) wave-PRIVATE slices, time-overlaid:
  //   (a) halo [100 px][24 ch] bf16; (b) r1 [64 rows][40 cols] bf16;
  //   (c) dx transpose [64 px][20] f32 (5120 B). No __syncthreads anywhere.
  __shared__ __align__(16) __bf16 smem[4 * 2560];

  const int tid = threadIdx.x;
  const int w = tid >> 6, l = tid & 63;
  __bf16* lds = smem + w * 2560;

  // XCD swizzle: round-robin dispatch -> XCD k handles batch image k.
  const int lin = (blockIdx.z * 16 + blockIdx.y) * 16 + blockIdx.x;
  const int swzb = (lin & 7) * 256 + (lin >> 3);
  const int b  = swzb >> 8;
  const int by = ((swzb >> 4) & 15) * 16;
  const int bx = (swzb & 15) * 16;
  const int by0 = by + (w >> 1) * 8;
  const int bx0 = bx + (w & 1) * 8;

  // ---- Stage 10x10 halo (reflect) as bf16, channel-interleaved pitch 24 ----
#pragma unroll
  for (int s = 0; s < 2; ++s) {
    int h = l + s * 64;
    if (h < 100) {
      int hy = h / 10, hx = h - hy * 10;
      int gy = by0 - 1 + hy; gy = (gy < 0) ? -gy : ((gy >= Hn) ? 2 * Hn - 2 - gy : gy);
      int gx = bx0 - 1 + hx; gx = (gx < 0) ? -gx : ((gx >= Wn) ? 2 * Wn - 2 - gx : gx);
      const int idx = gy * Wn + gx;
      bf16x8 q0, q1; bf16x4 q2;
      if constexpr (SIN == 0) {
        const float* sp = src + (size_t)b * Cn * HW + idx;
#pragma unroll
        for (int c = 0; c < 8; ++c)  q0[c] = (__bf16)sp[(size_t)c * HW];
#pragma unroll
        for (int c = 0; c < 8; ++c)  q1[c] = (__bf16)sp[(size_t)(c + 8) * HW];
#pragma unroll
        for (int c = 0; c < 4; ++c)  q2[c] = (__bf16)sp[(size_t)(c + 16) * HW];
      } else {
        const f32x4* pb = (const f32x4*)src;
        f32x4 v0 = pb[(0 * Bsz + b) * HW + idx];
        f32x4 v1 = pb[(1 * Bsz + b) * HW + idx];
        f32x4 v2 = pb[(2 * Bsz + b) * HW + idx];
        f32x4 v3 = pb[(3 * Bsz + b) * HW + idx];
        f32x4 v4 = pb[(4 * Bsz + b) * HW + idx];
#pragma unroll
        for (int c = 0; c < 4; ++c) { q0[c] = (__bf16)v0[c]; q0[c + 4] = (__bf16)v1[c]; }
#pragma unroll
        for (int c = 0; c < 4; ++c) { q1[c] = (__bf16)v2[c]; q1[c + 4] = (__bf16)v3[c]; }
#pragma unroll
        for (int c = 0; c < 4; ++c)  q2[c] = (__bf16)v4[c];
      }
      __bf16* wp = lds + h * 24;
      *(bf16x8*)(wp)      = q0;
      *(bf16x8*)(wp + 8)  = q1;
      *(bf16x4*)(wp + 16) = q2;
    }
  }

  // Fire mask in the load shadow: lane l owns pixel l (y=l>>3, x=l&7).
  const int py = l >> 3, px_ = l & 7;
  uint32_t y0, y1;
  tf2x32(ka, kb_key, 0u, (uint32_t)((b * Hn + by0 + py) * Wn + bx0 + px_), y0, y1);
  const unsigned long long fmask = __ballot(((y0 ^ y1) & 0x80000000u) == 0u);

  // ---- Depthwise conv (fp32 math, bf16 taps); own pixel only ----
  float a1[Cn], a2[Cn];
#pragma unroll
  for (int c = 0; c < Cn; ++c) { a1[c] = 0.f; a2[c] = 0.f; }
  bf16x8 id0, id1; bf16x4 id2;   // center tap = identity slots of perc

#pragma unroll
  for (int ky = 0; ky < 3; ++ky)
#pragma unroll
    for (int kx = 0; kx < 3; ++kx) {
      const __bf16* tp = lds + ((py + ky) * 10 + px_ + kx) * 24;
      bf16x8 t0 = *(const bf16x8*)(tp);
      bf16x8 t1 = *(const bf16x8*)(tp + 8);
      bf16x4 t2 = *(const bf16x4*)(tp + 16);
      if (ky == 1 && kx == 1) { id0 = t0; id1 = t1; id2 = t2; }
      const int tap = ky * 3 + kx;
#pragma unroll
      for (int c = 0; c < 8; ++c) {
        float v = (float)t0[c];
        a1[c] = fmaf(g_wf1[c * 9 + tap], v, a1[c]);
        a2[c] = fmaf(g_wf2[c * 9 + tap], v, a2[c]);
      }
#pragma unroll
      for (int c = 0; c < 8; ++c) {
        float v = (float)t1[c];
        a1[c + 8] = fmaf(g_wf1[(c + 8) * 9 + tap], v, a1[c + 8]);
        a2[c + 8] = fmaf(g_wf2[(c + 8) * 9 + tap], v, a2[c + 8]);
      }
#pragma unroll
      for (int c = 0; c < 4; ++c) {
        float v = (float)t2[c];
        a1[c + 16] = fmaf(g_wf1[(c + 16) * 9 + tap], v, a1[c + 16]);
        a2[c + 16] = fmaf(g_wf2[(c + 16) * 9 + tap], v, a2[c + 16]);
      }
    }

  // ---- Pack perc -> r1 (32-k chunks), load A-fragments (M=64) ----
  const int g4 = l >> 4, c16 = l & 15;

  bf16x8 af[4][2];
#pragma unroll
  for (int kb = 0; kb < 2; ++kb) {
#pragma unroll
    for (int g2 = 0; g2 < 4; ++g2) {
      bf16x8 pk;
#pragma unroll
      for (int e = 0; e < 8; ++e) {
        const int k = kb * 32 + g2 * 8 + e;
        __bf16 v;
        if      (k < 8)  v = id0[k];
        else if (k < 16) v = id1[k - 8];
        else if (k < 20) v = id2[k - 16];
        else if (k < 40) v = (__bf16)a1[k - 20];
        else if (k < 60) v = (__bf16)a2[k - 40];
        else             v = (__bf16)0.f;
        pk[e] = v;
      }
      *(bf16x8*)(lds + l * 40 + g2 * 8) = pk;   // overlays halo (own row l)
    }
    // same-wave LDS ops are in-order: all lanes' writes precede these reads
#pragma unroll
    for (int mt = 0; mt < 4; ++mt)
      af[mt][kb] = *(const bf16x8*)(lds + (mt * 16 + c16) * 40 + g4 * 8);
  }

  // ---- GEMM chunks: per 32 j's: GEMM1 -> H chunk (LDS) -> GEMM2 (swapped) ----
  const f32x4 zero4 = {0.f, 0.f, 0.f, 0.f};
  f32x4 acc2[2][4];   // [mt: ch 0..15 / 16..31][nt: 16-px groups]
#pragma unroll
  for (int mt = 0; mt < 2; ++mt)
#pragma unroll
    for (int nt = 0; nt < 4; ++nt) acc2[mt][nt] = zero4;

  const bf16x8* w1v = (const bf16x8*)g_W1p;
  const bf16x8* w2v = (const bf16x8*)g_W2p;

  for (int ch4 = 0; ch4 < 4; ++ch4) {
#pragma unroll
    for (int nt = 0; nt < 2; ++nt) {
      bf16x8 bw0 = w1v[((ch4 * 2 + nt) * 2 + 0) * 64 + l];
      bf16x8 bw1 = w1v[((ch4 * 2 + nt) * 2 + 1) * 64 + l];
      const float bias = b1[ch4 * 32 + nt * 16 + c16];
#pragma unroll
      for (int mt = 0; mt < 4; ++mt) {
        f32x4 a = mfma16(af[mt][0], bw0, zero4);
        a = mfma16(af[mt][1], bw1, a);
#pragma unroll
        for (int r = 0; r < 4; ++r) {
          float hv = fmaxf(a[r] + bias, 0.f);
          lds[(mt * 16 + g4 * 4 + r) * 40 + nt * 16 + c16] = (__bf16)hv;
        }
      }
    }
    bf16x8 wa0 = w2v[(0 * 4 + ch4) * 64 + l];
    bf16x8 wa1 = w2v[(1 * 4 + ch4) * 64 + l];
#pragma unroll
    for (int nt = 0; nt < 4; ++nt) {
      bf16x8 hb = *(const bf16x8*)(lds + (nt * 16 + c16) * 40 + g4 * 8);
      acc2[0][nt] = mfma16(wa0, hb, acc2[0][nt]);
      acc2[1][nt] = mfma16(wa1, hb, acc2[1][nt]);
    }
  }

  // ---- Epilogue ----
  if constexpr (SOUT == 1) {
    // dx transpose via LDS (r1 region is free after last GEMM2 read).
    float* ldsf = (float*)lds;
#pragma unroll
    for (int nt = 0; nt < 4; ++nt) {
      const int px = nt * 16 + c16;
      *(f32x4*)(ldsf + px * 20 + g4 * 4) = acc2[0][nt];
      if (g4 == 0) *(f32x4*)(ldsf + px * 20 + 16) = acc2[1][nt];
    }
    // Own pixel: 5 dense plane reads (x) + 5 dense stores.
    const int idx = (by0 + py) * Wn + (bx0 + px_);
    const float fire = ((fmask >> l) & 1ull) ? 1.f : 0.f;
    f32x4* db = (f32x4*)dst;
#pragma unroll
    for (int p = 0; p < 5; ++p) {
      f32x4 dxv = *(const f32x4*)(ldsf + l * 20 + p * 4);
      f32x4 xv;
      if constexpr (SIN == 0) {
        const float* sp = src + (size_t)b * Cn * HW + idx;
#pragma unroll
        for (int r = 0; r < 4; ++r) xv[r] = sp[(size_t)(p * 4 + r) * HW];
      } else {
        xv = ((const f32x4*)src)[(p * Bsz + b) * HW + idx];
      }
      f32x4 ov;
#pragma unroll
      for (int r = 0; r < 4; ++r) ov[r] = xv[r] + dxv[r] * fire;
      db[(p * Bsz + b) * HW + idx] = ov;
    }
  } else {
    // NCHW out (final step; SIN==1). D: px = nt*16+c16, ch = mt*16+g4*4+r.
    float* __restrict__ ob = dst + (size_t)b * Cn * HW;
#pragma unroll
    for (int nt = 0; nt < 4; ++nt) {
      const int pxl = nt * 16 + c16;
      const int gy = by0 + (pxl >> 3), gx = bx0 + (pxl & 7);
      const size_t pix = (size_t)gy * Wn + gx;
      const float fire = ((fmask >> pxl) & 1ull) ? 1.f : 0.f;
#pragma unroll
      for (int mt = 0; mt < 2; ++mt) {
        if (mt == 0 || g4 == 0) {
          f32x4 xv = ((const f32x4*)src)[((mt * 4 + g4) * Bsz + b) * HW + pix];
#pragma unroll
          for (int r = 0; r < 4; ++r) {
            const int ch = mt * 16 + g4 * 4 + r;
            ob[(size_t)ch * HW + pix] = xv[r] + acc2[mt][nt][r] * fire;
          }
        }
      }
    }
  }
}

extern "C" void kernel_launch(void* const* d_in, const int* in_sizes, int n_in,
                              void* d_out, int out_size, void* d_ws, size_t ws_size,
                              hipStream_t stream) {
  const float* x   = (const float*)d_in[0];
  const float* wf1 = (const float*)d_in[1];
  const float* wf2 = (const float*)d_in[2];
  const float* W1  = (const float*)d_in[3];
  const float* b1  = (const float*)d_in[4];
  const float* W2  = (const float*)d_in[5];

  float* out = (float*)d_out;
  float* ws0 = (float*)d_ws;   // 41.94 MB = exactly one plane set

  pack_weights<<<8, 256, 0, stream>>>(W1, W2, wf1, wf2);

  dim3 grid(16, 16, Bsz);
  dim3 blk(256);

  // s0: x(NCHW)->ws(PLANE); s1: ws->out(PLANE); s2: out->ws(PLANE);
  // s3: ws->out(NCHW). d_out doubles as plane scratch mid-sequence.
  uint32_t ka, kb;
  tf2x32(0u, 42u, 0u, 0u, ka, kb);
  nca_step<0, 1><<<grid, blk, 0, stream>>>(x,   ws0, b1, ka, kb);
  tf2x32(0u, 42u, 0u, 1u, ka, kb);
  nca_step<1, 1><<<grid, blk, 0, stream>>>(ws0, out, b1, ka, kb);
  tf2x32(0u, 42u, 0u, 2u, ka, kb);
  nca_step<1, 1><<<grid, blk, 0, stream>>>(out, ws0, b1, ka, kb);
  tf2x32(0u, 42u, 0u, 3u, ka, kb);
  nca_step<1, 0><<<grid, blk, 0, stream>>>(ws0, out, b1, ka, kb);
}

// Round 11
// 143.234 us; speedup vs baseline: 2.2793x; 1.0585x over previous
//
#include <hip/hip_runtime.h>
#include <stdint.h>

// NCA step v11: flat 64x4 block tiles for contiguous DRAM segments.
//  - Block stages a 6x66 halo (bf16, ch-interleaved pitch 24) cooperatively:
//    PLANE reads land in 1056-B contiguous runs, ~8 dwordx4 in flight/lane.
//    One __syncthreads (halo), then waves are autonomous (each owns 1 row).
//  - GEMM1 operand-swapped (A=W1 frags, B=perc regs; same packed bytes as
//    before since A/B fragment lane layouts coincide) -> H stored with
//    ds_write_b64 (32 ops) instead of 128 b16; bias via f32x4.
//  - PLANE fp32 intermediates (v10): 5 planes of [b][px][4ch]; steps 0/3
//    convert from/to NCHW. d_ws/d_out ping-pong.
// B=8, C=20, H=W=256, HID=128, K_in=60 (pad 64), steps=4.

#define Bsz 8
#define Cn  20
#define Hn  256
#define Wn  256
#define HW  (Hn*Wn)

typedef float  f32x4  __attribute__((ext_vector_type(4)));
typedef __bf16 bf16x8 __attribute__((ext_vector_type(8)));
typedef __bf16 bf16x4 __attribute__((ext_vector_type(4)));
typedef short  s16x8  __attribute__((ext_vector_type(8)));

// Prepacked MFMA weight fragments + conv filters (rewritten each launch).
__device__ __bf16 g_W1p[128 * 64];        // GEMM1 A-frags (same bytes as v10 B-frags)
__device__ __bf16 g_W2p[2 * 4 * 64 * 8];  // GEMM2 A-frags
__device__ float  g_wf1[Cn * 9];
__device__ float  g_wf2[Cn * 9];

// Threefry-2x32, 20 rounds (verified r1: matches jax threefry_partitionable).
__device__ __host__ __forceinline__ void tf2x32(uint32_t k0, uint32_t k1,
                                                uint32_t x0, uint32_t x1,
                                                uint32_t& o0, uint32_t& o1) {
  uint32_t ks2 = k0 ^ k1 ^ 0x1BD11BDAu;
  x0 += k0; x1 += k1;
#define TFR(r) { x0 += x1; x1 = (x1 << (r)) | (x1 >> (32 - (r))); x1 ^= x0; }
  TFR(13) TFR(15) TFR(26) TFR(6)
  x0 += k1;  x1 += ks2 + 1u;
  TFR(17) TFR(29) TFR(16) TFR(24)
  x0 += ks2; x1 += k0 + 2u;
  TFR(13) TFR(15) TFR(26) TFR(6)
  x0 += k0;  x1 += k1 + 3u;
  TFR(17) TFR(29) TFR(16) TFR(24)
  x0 += k1;  x1 += ks2 + 4u;
  TFR(13) TFR(15) TFR(26) TFR(6)
  x0 += ks2; x1 += k0 + 5u;
#undef TFR
  o0 = x0; o1 = x1;
}

__device__ __forceinline__ f32x4 mfma16(bf16x8 a, bf16x8 b, f32x4 c) {
  return __builtin_amdgcn_mfma_f32_16x16x32_bf16(
      __builtin_bit_cast(s16x8, a), __builtin_bit_cast(s16x8, b), c, 0, 0, 0);
}

// W1p: i = (((q*2+jt)*2+kb)*64 + l)*8 + e:
//   j = q*32+jt*16+(l&15), k = kb*32+(l>>4)*8+e -> W1[j][k] (k<60 else 0).
//   (A-frag and B-frag lane layouts coincide for 16x16x32.)
// W2p: i = ((mt*4+q)*512 + l*8 + e): ch = mt*16+(l&15), j = q*32+(l>>4)*8+e
//   -> W2[ch][j] for 3<=ch<20 else 0.
__global__ void pack_weights(const float* __restrict__ W1, const float* __restrict__ W2,
                             const float* __restrict__ wf1, const float* __restrict__ wf2) {
  int t = blockIdx.x * 256 + threadIdx.x;
  for (int i = t; i < 128 * 64; i += gridDim.x * 256) {
    int e = i & 7, l = (i >> 3) & 63, kb = (i >> 9) & 1, jt = (i >> 10) & 1, q = i >> 11;
    int j = q * 32 + jt * 16 + (l & 15);
    int k = kb * 32 + (l >> 4) * 8 + e;
    g_W1p[i] = (k < 60) ? (__bf16)W1[j * 60 + k] : (__bf16)0.f;
  }
  for (int i = t; i < 2 * 4 * 512; i += gridDim.x * 256) {
    int e = i & 7, l = (i >> 3) & 63, q = (i >> 9) & 3, mt = i >> 11;
    int ch = mt * 16 + (l & 15);
    int j  = q * 32 + (l >> 4) * 8 + e;
    g_W2p[i] = (ch >= 3 && ch < Cn) ? (__bf16)W2[ch * 128 + j] : (__bf16)0.f;
  }
  for (int i = t; i < Cn * 9; i += gridDim.x * 256) {
    g_wf1[i] = wf1[i];
    g_wf2[i] = wf2[i];
  }
}

// SIN/SOUT: 0 = NCHW fp32 (harness x / final out), 1 = PLANE fp32.
template <int SIN, int SOUT>
__global__ __launch_bounds__(256, 4) void nca_step(
    const float* __restrict__ src, float* __restrict__ dst,
    const float* __restrict__ b1, uint32_t ka, uint32_t kb_key) {

  // halo: block-shared [6 rows][66 px][24 ch] bf16 = 19008 B.
  // r1  : per-wave [64 rows][40 cols] bf16 slices (perc/H chunks, dx f32).
  __shared__ __align__(16) __bf16 halo[6 * 66 * 24];
  __shared__ __align__(16) __bf16 r1all[4 * 2560];

  const int tid = threadIdx.x;
  const int w = tid >> 6, l = tid & 63;
  __bf16* r1 = r1all + w * 2560;

  // XCD swizzle: round-robin dispatch -> XCD k handles batch image k.
  const int lin = (blockIdx.z * 64 + blockIdx.y) * 4 + blockIdx.x;
  const int swzb = (lin & 7) * 256 + (lin >> 3);
  const int b   = swzb >> 8;
  const int rem = swzb & 255;
  const int by0 = (rem >> 2) * 4;       // tile row base (4 rows per block)
  const int bx0 = (rem & 3) * 64;       // tile col base (64 px per row)

  // ---- Stage 6x66 halo (reflect), channel-interleaved bf16 pitch 24 ----
  for (int t = tid; t < 6 * 66; t += 256) {
    int ry = t / 66, cx = t - ry * 66;
    int gy = by0 - 1 + ry; gy = (gy < 0) ? -gy : ((gy >= Hn) ? 2 * Hn - 2 - gy : gy);
    int gx = bx0 - 1 + cx; gx = (gx < 0) ? -gx : ((gx >= Wn) ? 2 * Wn - 2 - gx : gx);
    const int idx = gy * Wn + gx;
    bf16x8 q0, q1; bf16x4 q2;
    if constexpr (SIN == 0) {
      const float* sp = src + (size_t)b * Cn * HW + idx;
#pragma unroll
      for (int c = 0; c < 8; ++c)  q0[c] = (__bf16)sp[(size_t)c * HW];
#pragma unroll
      for (int c = 0; c < 8; ++c)  q1[c] = (__bf16)sp[(size_t)(c + 8) * HW];
#pragma unroll
      for (int c = 0; c < 4; ++c)  q2[c] = (__bf16)sp[(size_t)(c + 16) * HW];
    } else {
      const f32x4* pb = (const f32x4*)src;
      f32x4 v0 = pb[(0 * Bsz + b) * HW + idx];
      f32x4 v1 = pb[(1 * Bsz + b) * HW + idx];
      f32x4 v2 = pb[(2 * Bsz + b) * HW + idx];
      f32x4 v3 = pb[(3 * Bsz + b) * HW + idx];
      f32x4 v4 = pb[(4 * Bsz + b) * HW + idx];
#pragma unroll
      for (int c = 0; c < 4; ++c) { q0[c] = (__bf16)v0[c]; q0[c + 4] = (__bf16)v1[c]; }
#pragma unroll
      for (int c = 0; c < 4; ++c) { q1[c] = (__bf16)v2[c]; q1[c + 4] = (__bf16)v3[c]; }
#pragma unroll
      for (int c = 0; c < 4; ++c)  q2[c] = (__bf16)v4[c];
    }
    __bf16* wp = halo + t * 24;
    *(bf16x8*)(wp)      = q0;
    *(bf16x8*)(wp + 8)  = q1;
    *(bf16x4*)(wp + 16) = q2;
  }

  // Fire mask in the load shadow: wave w owns image row gy=by0+w, lane l
  // owns pixel gx = bx0 + l.
  const int gy = by0 + w;
  uint32_t y0, y1;
  tf2x32(ka, kb_key, 0u, (uint32_t)((b * Hn + gy) * Wn + bx0 + l), y0, y1);
  const unsigned long long fmask = __ballot(((y0 ^ y1) & 0x80000000u) == 0u);

  __syncthreads();   // halo visible to all waves; the only barrier

  // ---- Depthwise conv (fp32 math, bf16 taps); lane l = pixel (gy, bx0+l) ----
  float a1[Cn], a2[Cn];
#pragma unroll
  for (int c = 0; c < Cn; ++c) { a1[c] = 0.f; a2[c] = 0.f; }
  bf16x8 id0, id1; bf16x4 id2;   // center tap = identity slots of perc

#pragma unroll
  for (int ky = 0; ky < 3; ++ky)
#pragma unroll
    for (int kx = 0; kx < 3; ++kx) {
      const __bf16* tp = halo + ((w + ky) * 66 + l + kx) * 24;
      bf16x8 t0 = *(const bf16x8*)(tp);
      bf16x8 t1 = *(const bf16x8*)(tp + 8);
      bf16x4 t2 = *(const bf16x4*)(tp + 16);
      if (ky == 1 && kx == 1) { id0 = t0; id1 = t1; id2 = t2; }
      const int tap = ky * 3 + kx;
#pragma unroll
      for (int c = 0; c < 8; ++c) {
        float v = (float)t0[c];
        a1[c] = fmaf(g_wf1[c * 9 + tap], v, a1[c]);
        a2[c] = fmaf(g_wf2[c * 9 + tap], v, a2[c]);
      }
#pragma unroll
      for (int c = 0; c < 8; ++c) {
        float v = (float)t1[c];
        a1[c + 8] = fmaf(g_wf1[(c + 8) * 9 + tap], v, a1[c + 8]);
        a2[c + 8] = fmaf(g_wf2[(c + 8) * 9 + tap], v, a2[c + 8]);
      }
#pragma unroll
      for (int c = 0; c < 4; ++c) {
        float v = (float)t2[c];
        a1[c + 16] = fmaf(g_wf1[(c + 16) * 9 + tap], v, a1[c + 16]);
        a2[c + 16] = fmaf(g_wf2[(c + 16) * 9 + tap], v, a2[c + 16]);
      }
    }

  // ---- Pack perc -> r1 (32-k chunks), load perc fragments (M=64 px) ----
  const int g4 = l >> 4, c16 = l & 15;

  bf16x8 af[4][2];
#pragma unroll
  for (int kb = 0; kb < 2; ++kb) {
#pragma unroll
    for (int g2 = 0; g2 < 4; ++g2) {
      bf16x8 pk;
#pragma unroll
      for (int e = 0; e < 8; ++e) {
        const int k = kb * 32 + g2 * 8 + e;
        __bf16 v;
        if      (k < 8)  v = id0[k];
        else if (k < 16) v = id1[k - 8];
        else if (k < 20) v = id2[k - 16];
        else if (k < 40) v = (__bf16)a1[k - 20];
        else if (k < 60) v = (__bf16)a2[k - 40];
        else             v = (__bf16)0.f;
        pk[e] = v;
      }
      *(bf16x8*)(r1 + l * 40 + g2 * 8) = pk;   // own row l (wave-private slice)
    }
    // same-wave LDS ops are in-order: all lanes' writes precede these reads
#pragma unroll
    for (int pxt = 0; pxt < 4; ++pxt)
      af[pxt][kb] = *(const bf16x8*)(r1 + (pxt * 16 + c16) * 40 + g4 * 8);
  }

  // ---- GEMM chunks: per 32 j's: GEMM1 (swapped) -> H chunk -> GEMM2 ----
  const f32x4 zero4 = {0.f, 0.f, 0.f, 0.f};
  f32x4 acc2[2][4];
#pragma unroll
  for (int mt = 0; mt < 2; ++mt)
#pragma unroll
    for (int nt = 0; nt < 4; ++nt) acc2[mt][nt] = zero4;

  const bf16x8* w1v = (const bf16x8*)g_W1p;
  const bf16x8* w2v = (const bf16x8*)g_W2p;

  for (int q = 0; q < 4; ++q) {
    // GEMM1 swapped: D[j-in-32][px] = Weff_q @ perc^T; lane: col=c16 -> px,
    // row=g4*4+r -> j. H store = one b64 per (jt,pxt).
#pragma unroll
    for (int jt = 0; jt < 2; ++jt) {
      bf16x8 aw0 = w1v[((q * 2 + jt) * 2 + 0) * 64 + l];
      bf16x8 aw1 = w1v[((q * 2 + jt) * 2 + 1) * 64 + l];
      const f32x4 bias = *(const f32x4*)(b1 + q * 32 + jt * 16 + g4 * 4);
#pragma unroll
      for (int pxt = 0; pxt < 4; ++pxt) {
        f32x4 a = mfma16(aw0, af[pxt][0], zero4);
        a = mfma16(aw1, af[pxt][1], a);
        bf16x4 hv;
#pragma unroll
        for (int r = 0; r < 4; ++r)
          hv[r] = (__bf16)fmaxf(a[r] + bias[r], 0.f);
        *(bf16x4*)(r1 + (pxt * 16 + c16) * 40 + jt * 16 + g4 * 4) = hv;
      }
    }
    // GEMM2: dx[ch][px] += W2_q @ H_q^T (H cols 0..31 time-multiplexed)
    bf16x8 wa0 = w2v[(0 * 4 + q) * 64 + l];
    bf16x8 wa1 = w2v[(1 * 4 + q) * 64 + l];
#pragma unroll
    for (int nt = 0; nt < 4; ++nt) {
      bf16x8 hb = *(const bf16x8*)(r1 + (nt * 16 + c16) * 40 + g4 * 8);
      acc2[0][nt] = mfma16(wa0, hb, acc2[0][nt]);
      acc2[1][nt] = mfma16(wa1, hb, acc2[1][nt]);
    }
  }

  // ---- Epilogue ----
  if constexpr (SOUT == 1) {
    // dx transpose via LDS (r1 slice free now): [64 px][20ch] f32 = 5120 B.
    float* ldsf = (float*)r1;
#pragma unroll
    for (int nt = 0; nt < 4; ++nt) {
      const int px = nt * 16 + c16;
      *(f32x4*)(ldsf + px * 20 + g4 * 4) = acc2[0][nt];
      if (g4 == 0) *(f32x4*)(ldsf + px * 20 + 16) = acc2[1][nt];
    }
    // Own pixel: 5 dense plane reads (x) + 5 dense stores (1 KB/wave each).
    const int idx = gy * Wn + bx0 + l;
    const float fire = ((fmask >> l) & 1ull) ? 1.f : 0.f;
    f32x4* db = (f32x4*)dst;
#pragma unroll
    for (int p = 0; p < 5; ++p) {
      f32x4 dxv = *(const f32x4*)(ldsf + l * 20 + p * 4);
      f32x4 xv;
      if constexpr (SIN == 0) {
        const float* sp = src + (size_t)b * Cn * HW + idx;
#pragma unroll
        for (int r = 0; r < 4; ++r) xv[r] = sp[(size_t)(p * 4 + r) * HW];
      } else {
        xv = ((const f32x4*)src)[(p * Bsz + b) * HW + idx];
      }
      f32x4 ov;
#pragma unroll
      for (int r = 0; r < 4; ++r) ov[r] = xv[r] + dxv[r] * fire;
      db[(p * Bsz + b) * HW + idx] = ov;
    }
  } else {
    // NCHW out (final step; SIN==1). D: px = nt*16+c16, ch = mt*16+g4*4+r.
    float* __restrict__ ob = dst + (size_t)b * Cn * HW;
#pragma unroll
    for (int nt = 0; nt < 4; ++nt) {
      const int pxl = nt * 16 + c16;
      const size_t pix = (size_t)gy * Wn + bx0 + pxl;
      const float fire = ((fmask >> pxl) & 1ull) ? 1.f : 0.f;
#pragma unroll
      for (int mt = 0; mt < 2; ++mt) {
        if (mt == 0 || g4 == 0) {
          f32x4 xv = ((const f32x4*)src)[((mt * 4 + g4) * Bsz + b) * HW + pix];
#pragma unroll
          for (int r = 0; r < 4; ++r) {
            const int ch = mt * 16 + g4 * 4 + r;
            ob[(size_t)ch * HW + pix] = xv[r] + acc2[mt][nt][r] * fire;
          }
        }
      }
    }
  }
}

extern "C" void kernel_launch(void* const* d_in, const int* in_sizes, int n_in,
                              void* d_out, int out_size, void* d_ws, size_t ws_size,
                              hipStream_t stream) {
  const float* x   = (const float*)d_in[0];
  const float* wf1 = (const float*)d_in[1];
  const float* wf2 = (const float*)d_in[2];
  const float* W1  = (const float*)d_in[3];
  const float* b1  = (const float*)d_in[4];
  const float* W2  = (const float*)d_in[5];

  float* out = (float*)d_out;
  float* ws0 = (float*)d_ws;   // 41.94 MB = exactly one plane set

  pack_weights<<<8, 256, 0, stream>>>(W1, W2, wf1, wf2);

  dim3 grid(4, 64, Bsz);   // 64-wide x 4-tall tiles
  dim3 blk(256);

  // s0: x(NCHW)->ws(PLANE); s1: ws->out(PLANE); s2: out->ws(PLANE);
  // s3: ws->out(NCHW). d_out doubles as plane scratch mid-sequence.
  uint32_t ka, kb;
  tf2x32(0u, 42u, 0u, 0u, ka, kb);
  nca_step<0, 1><<<grid, blk, 0, stream>>>(x,   ws0, b1, ka, kb);
  tf2x32(0u, 42u, 0u, 1u, ka, kb);
  nca_step<1, 1><<<grid, blk, 0, stream>>>(ws0, out, b1, ka, kb);
  tf2x32(0u, 42u, 0u, 2u, ka, kb);
  nca_step<1, 1><<<grid, blk, 0, stream>>>(out, ws0, b1, ka, kb);
  tf2x32(0u, 42u, 0u, 3u, ka, kb);
  nca_step<1, 0><<<grid, blk, 0, stream>>>(ws0, out, b1, ka, kb);
}